// Round 2
// baseline (560.926 us; speedup 1.0000x reference)
//
#include <hip/hip_runtime.h>
#include <hip/hip_bf16.h>

#define N_NODES 8192
#define F_IN    128
#define F_OUT   64
#define GAT_ALPHA 0.2f
#define JSPLIT  16
#define COLS_PER_SPLIT (N_NODES / JSPLIT)   // 512
#define KSTEPS  (COLS_PER_SPLIT / 32)       // 16

typedef short  short8_t  __attribute__((ext_vector_type(8)));
typedef float  f32x4_t   __attribute__((ext_vector_type(4)));

static __device__ __forceinline__ unsigned short f32_to_bf16_bits(float x) {
    // round-to-nearest-even, finite inputs only
    unsigned int u = __float_as_uint(x);
    unsigned int r = (u + 0x7fffu + ((u >> 16) & 1u)) >> 16;
    return (unsigned short)r;
}

// Kernel 1: Wh = h @ W (fp32), store transposed bf16 wht[f][node]; s1 = Wh@a1, s2 = Wh@a2.
__global__ __launch_bounds__(256) void k_wh(
    const float* __restrict__ h, const float* __restrict__ W, const float* __restrict__ a,
    unsigned short* __restrict__ wht, float* __restrict__ s1, float* __restrict__ s2)
{
    __shared__ float Wl[F_IN][F_OUT];   // 32 KB
    int tid = threadIdx.x;
    #pragma unroll
    for (int i = 0; i < (F_IN * F_OUT) / 256; ++i) {
        int idx = tid + i * 256;
        Wl[idx >> 6][idx & 63] = W[idx];
    }
    __syncthreads();
    int wave = tid >> 6, lane = tid & 63;
    int row = blockIdx.x * 4 + wave;          // one wave per node row, lane = output feature
    const float* hr = h + (size_t)row * F_IN;
    float acc = 0.f;
    #pragma unroll
    for (int k = 0; k < F_IN; k += 4) {
        float4 hv = *(const float4*)(hr + k);  // broadcast across lanes (L1)
        acc += hv.x * Wl[k + 0][lane];
        acc += hv.y * Wl[k + 1][lane];
        acc += hv.z * Wl[k + 2][lane];
        acc += hv.w * Wl[k + 3][lane];
    }
    wht[(size_t)lane * N_NODES + row] = f32_to_bf16_bits(acc);
    float p1 = acc * a[lane];
    float p2 = acc * a[F_OUT + lane];
    #pragma unroll
    for (int off = 32; off > 0; off >>= 1) {
        p1 += __shfl_down(p1, off);
        p2 += __shfl_down(p2, off);
    }
    if (lane == 0) { s1[row] = p1; s2[row] = p2; }
}

// Kernel 2: single-pass masked-softmax-numerator + P@Wh via MFMA.
// Block = 4 waves; wave handles 16 rows; grid = 128 row-tiles * JSPLIT col-splits.
// Lane (q=lane>>4, m=lane&15): A-frag = p[row0+m][kstep*32 + q*8 + 0..7] (built in regs),
// B-frag t = wht[t*16+m][same k range] (contiguous 16B). C: row=q*4+reg, col=lane&15.
__global__ __launch_bounds__(256) void k_attn(
    const int* __restrict__ adj, const float* __restrict__ ef,
    const float* __restrict__ a,
    const float* __restrict__ s1, const float* __restrict__ s2,
    const unsigned short* __restrict__ wht,
    float* __restrict__ Osum, float* __restrict__ lsum)
{
    int tid  = threadIdx.x;
    int wave = tid >> 6, lane = tid & 63;
    int q = lane >> 4, m = lane & 15;
    int rowtile = blockIdx.x / JSPLIT;
    int split   = blockIdx.x % JSPLIT;
    int row0  = rowtile * 64 + wave * 16;
    int row_m = row0 + m;
    int jbase = split * COLS_PER_SPLIT;

    float s1v = s1[row_m];
    float a_e = a[2 * F_OUT];

    const int*   adjr = adj + (size_t)row_m * N_NODES + jbase;
    const float* efr  = ef  + (size_t)row_m * N_NODES + jbase;
    const float* s2r  = s2 + jbase;
    const unsigned short* wb = wht + jbase;
    const int coff = q * 8;

    f32x4_t acc0 = {0.f, 0.f, 0.f, 0.f};
    f32x4_t acc1 = acc0, acc2 = acc0, acc3 = acc0;
    float lac = 0.f;

    #pragma unroll 2
    for (int kk = 0; kk < KSTEPS; ++kk) {
        int c = kk * 32 + coff;
        int4   aj0 = *(const int4*)(adjr + c);
        int4   aj1 = *(const int4*)(adjr + c + 4);
        float4 ev0 = *(const float4*)(efr + c);
        float4 ev1 = *(const float4*)(efr + c + 4);
        float4 sv0 = *(const float4*)(s2r + c);
        float4 sv1 = *(const float4*)(s2r + c + 4);

        short8_t af;
        float e, p;
        e = fmaf(ev0.x, a_e, s1v + sv0.x); e = fmaxf(e, GAT_ALPHA * e); p = (aj0.x > 0) ? __expf(e) : 0.f; lac += p; af[0] = (short)f32_to_bf16_bits(p);
        e = fmaf(ev0.y, a_e, s1v + sv0.y); e = fmaxf(e, GAT_ALPHA * e); p = (aj0.y > 0) ? __expf(e) : 0.f; lac += p; af[1] = (short)f32_to_bf16_bits(p);
        e = fmaf(ev0.z, a_e, s1v + sv0.z); e = fmaxf(e, GAT_ALPHA * e); p = (aj0.z > 0) ? __expf(e) : 0.f; lac += p; af[2] = (short)f32_to_bf16_bits(p);
        e = fmaf(ev0.w, a_e, s1v + sv0.w); e = fmaxf(e, GAT_ALPHA * e); p = (aj0.w > 0) ? __expf(e) : 0.f; lac += p; af[3] = (short)f32_to_bf16_bits(p);
        e = fmaf(ev1.x, a_e, s1v + sv1.x); e = fmaxf(e, GAT_ALPHA * e); p = (aj1.x > 0) ? __expf(e) : 0.f; lac += p; af[4] = (short)f32_to_bf16_bits(p);
        e = fmaf(ev1.y, a_e, s1v + sv1.y); e = fmaxf(e, GAT_ALPHA * e); p = (aj1.y > 0) ? __expf(e) : 0.f; lac += p; af[5] = (short)f32_to_bf16_bits(p);
        e = fmaf(ev1.z, a_e, s1v + sv1.z); e = fmaxf(e, GAT_ALPHA * e); p = (aj1.z > 0) ? __expf(e) : 0.f; lac += p; af[6] = (short)f32_to_bf16_bits(p);
        e = fmaf(ev1.w, a_e, s1v + sv1.w); e = fmaxf(e, GAT_ALPHA * e); p = (aj1.w > 0) ? __expf(e) : 0.f; lac += p; af[7] = (short)f32_to_bf16_bits(p);

        const unsigned short* wp = wb + c;
        short8_t b0 = *(const short8_t*)(wp + (size_t)( 0 + m) * N_NODES);
        short8_t b1 = *(const short8_t*)(wp + (size_t)(16 + m) * N_NODES);
        short8_t b2 = *(const short8_t*)(wp + (size_t)(32 + m) * N_NODES);
        short8_t b3 = *(const short8_t*)(wp + (size_t)(48 + m) * N_NODES);

        acc0 = __builtin_amdgcn_mfma_f32_16x16x32_bf16(af, b0, acc0, 0, 0, 0);
        acc1 = __builtin_amdgcn_mfma_f32_16x16x32_bf16(af, b1, acc1, 0, 0, 0);
        acc2 = __builtin_amdgcn_mfma_f32_16x16x32_bf16(af, b2, acc2, 0, 0, 0);
        acc3 = __builtin_amdgcn_mfma_f32_16x16x32_bf16(af, b3, acc3, 0, 0, 0);
    }

    // row-sum l: lanes {m, m+16, m+32, m+48} hold partials for row_m
    lac += __shfl_xor(lac, 16);
    lac += __shfl_xor(lac, 32);
    if (q == 0) atomicAdd(&lsum[row_m], lac);

    #pragma unroll
    for (int r = 0; r < 4; ++r) {
        int orow = row0 + q * 4 + r;
        float* op = Osum + (size_t)orow * F_OUT + m;
        atomicAdd(op +  0, acc0[r]);
        atomicAdd(op + 16, acc1[r]);
        atomicAdd(op + 32, acc2[r]);
        atomicAdd(op + 48, acc3[r]);
    }
}

// Kernel 3: normalize + ELU
__global__ __launch_bounds__(256) void k_out(
    const float* __restrict__ Osum, const float* __restrict__ lsum, float* __restrict__ out)
{
    int i = blockIdx.x * 256 + threadIdx.x;
    float v = Osum[i] / lsum[i >> 6];
    out[i] = (v > 0.f) ? v : (__expf(v) - 1.f);
}

extern "C" void kernel_launch(void* const* d_in, const int* in_sizes, int n_in,
                              void* d_out, int out_size, void* d_ws, size_t ws_size,
                              hipStream_t stream)
{
    const float* h   = (const float*)d_in[0];
    const int*   adj = (const int*)d_in[1];
    const float* ef  = (const float*)d_in[2];
    const float* W   = (const float*)d_in[3];
    const float* a   = (const float*)d_in[4];
    float* out = (float*)d_out;

    // workspace layout (~3.2 MB total)
    char* ws = (char*)d_ws;
    unsigned short* wht = (unsigned short*)ws;                       // 64*8192*2 = 1 MB
    float* s1   = (float*)(ws + (size_t)F_OUT * N_NODES * 2);        // 32 KB
    float* s2   = s1 + N_NODES;                                      // 32 KB
    float* Osum = s2 + N_NODES;                                      // 2 MB
    float* lsum = Osum + (size_t)N_NODES * F_OUT;                    // 32 KB

    // ws is poisoned 0xAA before every launch: zero the accumulators
    hipMemsetAsync(Osum, 0, ((size_t)N_NODES * F_OUT + N_NODES) * sizeof(float), stream);

    k_wh  <<<N_NODES / 4, 256, 0, stream>>>(h, W, a, wht, s1, s2);
    k_attn<<<(N_NODES / 64) * JSPLIT, 256, 0, stream>>>(adj, ef, a, s1, s2, wht, Osum, lsum);
    k_out <<<(N_NODES * F_OUT) / 256, 256, 0, stream>>>(Osum, lsum, out);
}

// Round 3
// 557.608 us; speedup vs baseline: 1.0059x; 1.0059x over previous
//
#include <hip/hip_runtime.h>
#include <hip/hip_bf16.h>

#define N_NODES 8192
#define F_IN    128
#define F_OUT   64
#define GAT_ALPHA 0.2f
#define JSPLIT  16
#define COLS_PER_SPLIT (N_NODES / JSPLIT)   // 512
#define KC      128                          // columns per LDS chunk
#define NCHUNK  (COLS_PER_SPLIT / KC)        // 4
#define LDSTR   136                          // padded LDS row stride (bf16 elems)

typedef short  short8_t  __attribute__((ext_vector_type(8)));
typedef float  f32x4_t   __attribute__((ext_vector_type(4)));

static __device__ __forceinline__ unsigned int f32_to_bf16_bits(float x) {
    unsigned int u = __float_as_uint(x);
    return (u + 0x7fffu + ((u >> 16) & 1u)) >> 16;
}

// Kernel 1: Wh = h @ W (fp32), store transposed bf16 wht[f][node]; s1 = Wh@a1, s2 = Wh@a2.
__global__ __launch_bounds__(256) void k_wh(
    const float* __restrict__ h, const float* __restrict__ W, const float* __restrict__ a,
    unsigned short* __restrict__ wht, float* __restrict__ s1, float* __restrict__ s2)
{
    __shared__ float Wl[F_IN][F_OUT];   // 32 KB
    int tid = threadIdx.x;
    #pragma unroll
    for (int i = 0; i < (F_IN * F_OUT) / 256; ++i) {
        int idx = tid + i * 256;
        Wl[idx >> 6][idx & 63] = W[idx];
    }
    __syncthreads();
    int wave = tid >> 6, lane = tid & 63;
    int row = blockIdx.x * 4 + wave;          // one wave per node row, lane = output feature
    const float* hr = h + (size_t)row * F_IN;
    float acc = 0.f;
    #pragma unroll
    for (int k = 0; k < F_IN; k += 4) {
        float4 hv = *(const float4*)(hr + k);  // broadcast across lanes (L1)
        acc += hv.x * Wl[k + 0][lane];
        acc += hv.y * Wl[k + 1][lane];
        acc += hv.z * Wl[k + 2][lane];
        acc += hv.w * Wl[k + 3][lane];
    }
    wht[(size_t)lane * N_NODES + row] = (unsigned short)f32_to_bf16_bits(acc);
    float p1 = acc * a[lane];
    float p2 = acc * a[F_OUT + lane];
    #pragma unroll
    for (int off = 32; off > 0; off >>= 1) {
        p1 += __shfl_down(p1, off);
        p2 += __shfl_down(p2, off);
    }
    if (lane == 0) { s1[row] = p1; s2[row] = p2; }
}

// Kernel 2: coalesced-load phase A (p = masked exp numerator) -> LDS (padded tile)
//           -> phase B MFMA P@Wh with A-frags from LDS, B-frags from wht (L2).
// Block = 4 waves = 64 rows x 512 cols; grid = 128 rowtiles * JSPLIT.
__global__ __launch_bounds__(256, 4) void k_attn(
    const int* __restrict__ adj, const float* __restrict__ ef,
    const float* __restrict__ a,
    const float* __restrict__ s1, const float* __restrict__ s2,
    const unsigned short* __restrict__ wht,
    float* __restrict__ Osum, float* __restrict__ lsum)
{
    __shared__ unsigned short pl[64 * LDSTR];   // 17408 B, padded stride kills bank conflicts
    int tid  = threadIdx.x;
    int wave = tid >> 6, lane = tid & 63;
    int q = lane >> 4, m = lane & 15;
    int rowtile = blockIdx.x / JSPLIT;
    int split   = blockIdx.x % JSPLIT;
    int row0  = rowtile * 64;
    int jbase = split * COLS_PER_SPLIT;

    // phase-A geometry: thread covers rows {i*8 + (tid>>5)}, cols ca..ca+3 of each chunk
    int ca  = (tid & 31) * 4;
    int ra0 = tid >> 5;
    float a_e = a[2 * F_OUT];
    float s1v[8];
    #pragma unroll
    for (int i = 0; i < 8; ++i) s1v[i] = s1[row0 + i * 8 + ra0];

    const unsigned short* wm = wht + (size_t)m * N_NODES + jbase;

    f32x4_t acc0 = {0.f, 0.f, 0.f, 0.f};
    f32x4_t acc1 = acc0, acc2 = acc0, acc3 = acc0, accl = acc0;
    short8_t ones;
    #pragma unroll
    for (int i = 0; i < 8; ++i) ones[i] = (short)0x3F80;   // bf16 1.0

    for (int ch = 0; ch < NCHUNK; ++ch) {
        int cb = jbase + ch * KC + ca;
        float4 s2q = *(const float4*)(s2 + cb);
        int4   aj[8];
        float4 ev[8];
        #pragma unroll
        for (int i = 0; i < 8; ++i) {   // 16 coalesced loads in flight (1KB/wave-instr)
            size_t off = (size_t)(row0 + i * 8 + ra0) * N_NODES + cb;
            aj[i] = *(const int4*)(adj + off);
            ev[i] = *(const float4*)(ef + off);
        }
        #pragma unroll
        for (int i = 0; i < 8; ++i) {
            float b0 = s1v[i] + s2q.x, b1 = s1v[i] + s2q.y;
            float b2 = s1v[i] + s2q.z, b3 = s1v[i] + s2q.w;
            float e0 = fmaf(ev[i].x, a_e, b0); e0 = fmaxf(e0, GAT_ALPHA * e0);
            float e1 = fmaf(ev[i].y, a_e, b1); e1 = fmaxf(e1, GAT_ALPHA * e1);
            float e2 = fmaf(ev[i].z, a_e, b2); e2 = fmaxf(e2, GAT_ALPHA * e2);
            float e3 = fmaf(ev[i].w, a_e, b3); e3 = fmaxf(e3, GAT_ALPHA * e3);
            float p0 = (aj[i].x > 0) ? __expf(e0) : 0.f;
            float p1 = (aj[i].y > 0) ? __expf(e1) : 0.f;
            float p2 = (aj[i].z > 0) ? __expf(e2) : 0.f;
            float p3 = (aj[i].w > 0) ? __expf(e3) : 0.f;
            uint2 pk;
            pk.x = f32_to_bf16_bits(p0) | (f32_to_bf16_bits(p1) << 16);
            pk.y = f32_to_bf16_bits(p2) | (f32_to_bf16_bits(p3) << 16);
            *(uint2*)&pl[(i * 8 + ra0) * LDSTR + ca] = pk;
        }
        __syncthreads();
        // phase B: wave handles rows wave*16..+15, all 64 output features
        int arow = (wave * 16 + m) * LDSTR;
        #pragma unroll
        for (int kk = 0; kk < 4; ++kk) {
            short8_t af = *(const short8_t*)&pl[arow + kk * 32 + q * 8];
            const unsigned short* wp = wm + ch * KC + kk * 32 + q * 8;
            short8_t b0 = *(const short8_t*)(wp);
            short8_t b1 = *(const short8_t*)(wp + (size_t)16 * N_NODES);
            short8_t b2 = *(const short8_t*)(wp + (size_t)32 * N_NODES);
            short8_t b3 = *(const short8_t*)(wp + (size_t)48 * N_NODES);
            acc0 = __builtin_amdgcn_mfma_f32_16x16x32_bf16(af, b0, acc0, 0, 0, 0);
            acc1 = __builtin_amdgcn_mfma_f32_16x16x32_bf16(af, b1, acc1, 0, 0, 0);
            acc2 = __builtin_amdgcn_mfma_f32_16x16x32_bf16(af, b2, acc2, 0, 0, 0);
            acc3 = __builtin_amdgcn_mfma_f32_16x16x32_bf16(af, b3, acc3, 0, 0, 0);
            accl = __builtin_amdgcn_mfma_f32_16x16x32_bf16(af, ones, accl, 0, 0, 0);
        }
        __syncthreads();
    }

    #pragma unroll
    for (int r = 0; r < 4; ++r) {
        int orow = row0 + wave * 16 + q * 4 + r;
        float* op = Osum + (size_t)orow * F_OUT + m;
        atomicAdd(op +  0, acc0[r]);
        atomicAdd(op + 16, acc1[r]);
        atomicAdd(op + 32, acc2[r]);
        atomicAdd(op + 48, acc3[r]);
    }
    if (m == 0) {   // accl cols all equal; one lane per (q,r) row commits l
        #pragma unroll
        for (int r = 0; r < 4; ++r)
            atomicAdd(&lsum[row0 + wave * 16 + q * 4 + r], accl[r]);
    }
}

// Kernel 3: normalize + ELU
__global__ __launch_bounds__(256) void k_out(
    const float* __restrict__ Osum, const float* __restrict__ lsum, float* __restrict__ out)
{
    int i = blockIdx.x * 256 + threadIdx.x;
    float v = Osum[i] / lsum[i >> 6];
    out[i] = (v > 0.f) ? v : (__expf(v) - 1.f);
}

extern "C" void kernel_launch(void* const* d_in, const int* in_sizes, int n_in,
                              void* d_out, int out_size, void* d_ws, size_t ws_size,
                              hipStream_t stream)
{
    const float* h   = (const float*)d_in[0];
    const int*   adj = (const int*)d_in[1];
    const float* ef  = (const float*)d_in[2];
    const float* W   = (const float*)d_in[3];
    const float* a   = (const float*)d_in[4];
    float* out = (float*)d_out;

    char* ws = (char*)d_ws;
    unsigned short* wht = (unsigned short*)ws;                       // 1 MB
    float* s1   = (float*)(ws + (size_t)F_OUT * N_NODES * 2);        // 32 KB
    float* s2   = s1 + N_NODES;                                      // 32 KB
    float* Osum = s2 + N_NODES;                                      // 2 MB
    float* lsum = Osum + (size_t)N_NODES * F_OUT;                    // 32 KB

    hipMemsetAsync(Osum, 0, ((size_t)N_NODES * F_OUT + N_NODES) * sizeof(float), stream);

    k_wh  <<<N_NODES / 4, 256, 0, stream>>>(h, W, a, wht, s1, s2);
    k_attn<<<(N_NODES / 64) * JSPLIT, 256, 0, stream>>>(adj, ef, a, s1, s2, wht, Osum, lsum);
    k_out <<<(N_NODES * F_OUT) / 256, 256, 0, stream>>>(Osum, lsum, out);
}

// Round 4
// 548.903 us; speedup vs baseline: 1.0219x; 1.0159x over previous
//
#include <hip/hip_runtime.h>
#include <hip/hip_bf16.h>

#define N_NODES 8192
#define F_IN    128
#define F_OUT   64
#define GAT_ALPHA 0.2f
#define JSPLIT  16
#define COLS_PER_SPLIT (N_NODES / JSPLIT)   // 512
#define KC      64                           // columns per chunk
#define NCH     (COLS_PER_SPLIT / KC)        // 8
#define LSTR    72                           // padded LDS stride (bf16 elems, 144B: 16B-aligned rows)

typedef short  short8_t  __attribute__((ext_vector_type(8)));
typedef float  f32x4_t   __attribute__((ext_vector_type(4)));

static __device__ __forceinline__ unsigned int f32_to_bf16_bits(float x) {
    unsigned int u = __float_as_uint(x);
    return (u + 0x7fffu + ((u >> 16) & 1u)) >> 16;
}

// Kernel 1: Wh = h @ W (fp32), store transposed bf16 wht[f][node]; s1 = Wh@a1, s2 = Wh@a2.
__global__ __launch_bounds__(256) void k_wh(
    const float* __restrict__ h, const float* __restrict__ W, const float* __restrict__ a,
    unsigned short* __restrict__ wht, float* __restrict__ s1, float* __restrict__ s2)
{
    __shared__ float Wl[F_IN][F_OUT];   // 32 KB
    int tid = threadIdx.x;
    #pragma unroll
    for (int i = 0; i < (F_IN * F_OUT) / 256; ++i) {
        int idx = tid + i * 256;
        Wl[idx >> 6][idx & 63] = W[idx];
    }
    __syncthreads();
    int wave = tid >> 6, lane = tid & 63;
    int row = blockIdx.x * 4 + wave;
    const float* hr = h + (size_t)row * F_IN;
    float acc = 0.f;
    #pragma unroll
    for (int k = 0; k < F_IN; k += 4) {
        float4 hv = *(const float4*)(hr + k);
        acc += hv.x * Wl[k + 0][lane];
        acc += hv.y * Wl[k + 1][lane];
        acc += hv.z * Wl[k + 2][lane];
        acc += hv.w * Wl[k + 3][lane];
    }
    wht[(size_t)lane * N_NODES + row] = (unsigned short)f32_to_bf16_bits(acc);
    float p1 = acc * a[lane];
    float p2 = acc * a[F_OUT + lane];
    #pragma unroll
    for (int off = 32; off > 0; off >>= 1) {
        p1 += __shfl_down(p1, off);
        p2 += __shfl_down(p2, off);
    }
    if (lane == 0) { s1[row] = p1; s2[row] = p2; }
}

// Kernel 2: per-wave-independent, software-pipelined single pass.
// Wave handles 16 rows x 512 cols. No __syncthreads at all.
// Per chunk (K=64): [B-loads (oldest)] -> [compute p from prefetched regs]
// -> [prefetch next chunk (youngest, stays in flight)] -> [LDS p-tile write]
// -> [MFMA consuming B-loads only].
__global__ __launch_bounds__(256) void k_attn(
    const int* __restrict__ adj, const float* __restrict__ ef,
    const float* __restrict__ a,
    const float* __restrict__ s1, const float* __restrict__ s2,
    const unsigned short* __restrict__ wht,
    float* __restrict__ Osum, float* __restrict__ lsum)
{
    __shared__ unsigned short pl[4 * 2 * 16 * LSTR];   // 18432 B: 4 waves x 2 bufs x 16x72
    int tid  = threadIdx.x;
    int wave = tid >> 6, lane = tid & 63;
    int q = lane >> 4, m = lane & 15;
    int r  = lane >> 2;          // phase-A row 0..15 within wave tile
    int cq = lane & 3;           // phase-A column quarter (16 cols each)
    int rowtile = blockIdx.x / JSPLIT;
    int split   = blockIdx.x % JSPLIT;
    int row0  = rowtile * 64 + wave * 16;
    int jbase = split * COLS_PER_SPLIT;

    float a_e = a[2 * F_OUT];
    int Rr = row0 + r;
    float s1v = s1[Rr];
    const int*   adjr = adj + (size_t)Rr * N_NODES + jbase + cq * 16;
    const float* efr  = ef  + (size_t)Rr * N_NODES + jbase + cq * 16;
    const float* s2r  = s2 + jbase + cq * 16;
    unsigned short* plw = pl + wave * (2 * 16 * LSTR);
    const unsigned short* wm = wht + (size_t)m * N_NODES + jbase;

    f32x4_t acc0 = {0.f, 0.f, 0.f, 0.f};
    f32x4_t acc1 = acc0, acc2 = acc0, acc3 = acc0, accl = acc0;
    short8_t ones;
    #pragma unroll
    for (int i = 0; i < 8; ++i) ones[i] = (short)0x3F80;   // bf16 1.0

    // prologue: prefetch chunk 0 (48 VGPRs of stream data in flight)
    int4   aj[4];
    float4 ev[4], sv[4];
    #pragma unroll
    for (int u = 0; u < 4; ++u) {
        aj[u] = *(const int4*)  (adjr + u * 4);
        ev[u] = *(const float4*)(efr  + u * 4);
        sv[u] = *(const float4*)(s2r  + u * 4);
    }

    #pragma unroll 2
    for (int ch = 0; ch < NCH; ++ch) {
        // 1) B-fragment loads for this chunk (L1/L2-hot wht) — OLDEST vmem this iter
        const unsigned short* wp = wm + ch * KC + q * 8;
        short8_t b[8];
        #pragma unroll
        for (int kk = 0; kk < 2; ++kk)
            #pragma unroll
            for (int t = 0; t < 4; ++t)
                b[kk * 4 + t] = *(const short8_t*)(wp + (size_t)t * 16 * N_NODES + kk * 32);

        // 2) compute p from prefetched registers (frees aj/ev/sv)
        uint2 pk[4];
        #pragma unroll
        for (int u = 0; u < 4; ++u) {
            float e0 = fmaf(ev[u].x, a_e, s1v + sv[u].x); e0 = fmaxf(e0, GAT_ALPHA * e0);
            float e1 = fmaf(ev[u].y, a_e, s1v + sv[u].y); e1 = fmaxf(e1, GAT_ALPHA * e1);
            float e2 = fmaf(ev[u].z, a_e, s1v + sv[u].z); e2 = fmaxf(e2, GAT_ALPHA * e2);
            float e3 = fmaf(ev[u].w, a_e, s1v + sv[u].w); e3 = fmaxf(e3, GAT_ALPHA * e3);
            float p0 = (aj[u].x > 0) ? __expf(e0) : 0.f;
            float p1 = (aj[u].y > 0) ? __expf(e1) : 0.f;
            float p2 = (aj[u].z > 0) ? __expf(e2) : 0.f;
            float p3 = (aj[u].w > 0) ? __expf(e3) : 0.f;
            pk[u].x = f32_to_bf16_bits(p0) | (f32_to_bf16_bits(p1) << 16);
            pk[u].y = f32_to_bf16_bits(p2) | (f32_to_bf16_bits(p3) << 16);
        }

        // 3) prefetch next chunk — YOUNGEST vmem; stays outstanding through MFMA phase
        if (ch + 1 < NCH) {
            adjr += KC; efr += KC; s2r += KC;
            #pragma unroll
            for (int u = 0; u < 4; ++u) {
                aj[u] = *(const int4*)  (adjr + u * 4);
                ev[u] = *(const float4*)(efr  + u * 4);
                sv[u] = *(const float4*)(s2r  + u * 4);
            }
        }

        // 4) p-tile to wave-private LDS (double-buffered; wave-local => no barrier)
        unsigned short* pb = plw + (ch & 1) * (16 * LSTR);
        #pragma unroll
        for (int u = 0; u < 4; ++u)
            *(uint2*)&pb[r * LSTR + cq * 16 + u * 4] = pk[u];

        // 5) MFMA phase: A-frags from LDS, consume B-loads (vmcnt leaves prefetch alive)
        const unsigned short* pr = pb + m * LSTR;
        #pragma unroll
        for (int kk = 0; kk < 2; ++kk) {
            short8_t af = *(const short8_t*)&pr[kk * 32 + q * 8];
            acc0 = __builtin_amdgcn_mfma_f32_16x16x32_bf16(af, b[kk * 4 + 0], acc0, 0, 0, 0);
            acc1 = __builtin_amdgcn_mfma_f32_16x16x32_bf16(af, b[kk * 4 + 1], acc1, 0, 0, 0);
            acc2 = __builtin_amdgcn_mfma_f32_16x16x32_bf16(af, b[kk * 4 + 2], acc2, 0, 0, 0);
            acc3 = __builtin_amdgcn_mfma_f32_16x16x32_bf16(af, b[kk * 4 + 3], acc3, 0, 0, 0);
            accl = __builtin_amdgcn_mfma_f32_16x16x32_bf16(af, ones, accl, 0, 0, 0);
        }
    }

    #pragma unroll
    for (int rr = 0; rr < 4; ++rr) {
        int orow = row0 + q * 4 + rr;
        float* op = Osum + (size_t)orow * F_OUT + m;
        atomicAdd(op +  0, acc0[rr]);
        atomicAdd(op + 16, acc1[rr]);
        atomicAdd(op + 32, acc2[rr]);
        atomicAdd(op + 48, acc3[rr]);
    }
    if (m == 0) {
        #pragma unroll
        for (int rr = 0; rr < 4; ++rr)
            atomicAdd(&lsum[row0 + q * 4 + rr], accl[rr]);
    }
}

// Kernel 3: normalize + ELU
__global__ __launch_bounds__(256) void k_out(
    const float* __restrict__ Osum, const float* __restrict__ lsum, float* __restrict__ out)
{
    int i = blockIdx.x * 256 + threadIdx.x;
    float v = Osum[i] / lsum[i >> 6];
    out[i] = (v > 0.f) ? v : (__expf(v) - 1.f);
}

extern "C" void kernel_launch(void* const* d_in, const int* in_sizes, int n_in,
                              void* d_out, int out_size, void* d_ws, size_t ws_size,
                              hipStream_t stream)
{
    const float* h   = (const float*)d_in[0];
    const int*   adj = (const int*)d_in[1];
    const float* ef  = (const float*)d_in[2];
    const float* W   = (const float*)d_in[3];
    const float* a   = (const float*)d_in[4];
    float* out = (float*)d_out;

    char* ws = (char*)d_ws;
    unsigned short* wht = (unsigned short*)ws;                       // 1 MB
    float* s1   = (float*)(ws + (size_t)F_OUT * N_NODES * 2);        // 32 KB
    float* s2   = s1 + N_NODES;                                      // 32 KB
    float* Osum = s2 + N_NODES;                                      // 2 MB
    float* lsum = Osum + (size_t)N_NODES * F_OUT;                    // 32 KB

    hipMemsetAsync(Osum, 0, ((size_t)N_NODES * F_OUT + N_NODES) * sizeof(float), stream);

    k_wh  <<<N_NODES / 4, 256, 0, stream>>>(h, W, a, wht, s1, s2);
    k_attn<<<(N_NODES / 64) * JSPLIT, 256, 0, stream>>>(adj, ef, a, s1, s2, wht, Osum, lsum);
    k_out <<<(N_NODES * F_OUT) / 256, 256, 0, stream>>>(Osum, lsum, out);
}